// Round 8
// baseline (236.530 us; speedup 1.0000x reference)
//
#include <hip/hip_runtime.h>
#include <hip/hip_bf16.h>
#include <math.h>

#define H_DIM 64
#define G 64
#define ATT 1024
#define EMB 4
#define P 64
#define BB 2048   // batch B = S*P
#define MAXROWS 129088  // 2048*63 rounded up to multiple of 64
#define K1_BLOCKS 1057  // 1 init + 256 dec + 512 pool + 16 Wte + 16 Wot + 256 Wt
#define MAGICF 0x13579BDF
#define TAIL_BLOCKS 512

typedef __attribute__((ext_vector_type(8))) short short8;
typedef __attribute__((ext_vector_type(4))) float floatx4;

__device__ inline ushort f2bf(float v) {
    __hip_bfloat16 b = __float2bfloat16(v);
    return *(ushort*)&b;
}
__device__ inline float bf2f(ushort u) {
    union { float f; unsigned u32; } x;
    x.u32 = ((unsigned)u) << 16;
    return x.f;
}

// Grid-wide barrier for TAIL_BLOCKS co-resident blocks.
__device__ inline void grid_barrier(int* bar) {
    __syncthreads();
    if (threadIdx.x == 0) {
        __threadfence();
        __hip_atomic_fetch_add(bar, 1, __ATOMIC_ACQ_REL, __HIP_MEMORY_SCOPE_AGENT);
        while (__hip_atomic_load(bar, __ATOMIC_ACQUIRE, __HIP_MEMORY_SCOPE_AGENT) < TAIL_BLOCKS) {}
    }
    __syncthreads();
}

// ---------------- K1: init | dec(MFMA, self-contained) | pool | W_enc^T | W_out^T(pad96) | W_mlp^T ----------------
__global__ __launch_bounds__(256) void prep_kernel(const float* __restrict__ h,
                                                   const float* __restrict__ end_pos,
                                                   const float* __restrict__ W_enc,
                                                   const float* __restrict__ W_dec,
                                                   const float* __restrict__ W_out,
                                                   const float* __restrict__ W_mlp,
                                                   const float* __restrict__ b_dec,
                                                   const float* __restrict__ b_enc,
                                                   const float* __restrict__ w_full,
                                                   ushort* __restrict__ enc,
                                                   ushort* __restrict__ Wte,
                                                   ushort* __restrict__ Wot,
                                                   ushort* __restrict__ Wt,
                                                   float* __restrict__ dec_r,
                                                   float* __restrict__ s_part,
                                                   int* __restrict__ rowidx,
                                                   int* __restrict__ cntA,
                                                   int* __restrict__ baseA,
                                                   int* __restrict__ counter,
                                                   float* __restrict__ sums,
                                                   int* __restrict__ bar,
                                                   int* __restrict__ flag) {
    __shared__ __align__(16) char sm1[28672];
    __shared__ int nzS[4], baseSh[4];

    int blk = blockIdx.x;
    int t = threadIdx.x;

    if (blk == 0) {
        // ---- init: zero counter, sums, barrier counters; publish flag ----
        if (t < 64) __hip_atomic_store(&counter[t], 0, __ATOMIC_RELAXED, __HIP_MEMORY_SCOPE_AGENT);
        if (t < 64) __hip_atomic_store(&bar[t], 0, __ATOMIC_RELAXED, __HIP_MEMORY_SCOPE_AGENT);
        int* sz = (int*)sums;
        for (int i = t; i < 2048; i += 256)
            __hip_atomic_store(&sz[i], 0, __ATOMIC_RELAXED, __HIP_MEMORY_SCOPE_AGENT);
        __syncthreads();
        if (t == 0) __hip_atomic_store(flag, MAGICF, __ATOMIC_RELEASE, __HIP_MEMORY_SCOPE_AGENT);
    } else if (blk <= 256) {
        // ---- dec: self-contained MFMA tile 64 rows x 128 cols, K=64 ----
        int idx = blk - 1;                  // 0..255
        int m0 = (idx & 31) * 64, n1 = (idx >> 5) * 128;
        int w = t >> 6, lane = t & 63;
        int lm = lane & 15, q = lane >> 4;
        ushort (*Asm)[72] = (ushort(*)[72])sm1;                 // 64x72
        ushort (*Bsm)[72] = (ushort(*)[72])(sm1 + 9216);        // 128x72

        #pragma unroll
        for (int i = 0; i < 16; ++i) {      // A: h fp32 -> bf16, 64x64
            int flat = t + 256 * i;
            int r = flat >> 6, k = flat & 63;
            Asm[r][k] = f2bf(h[(size_t)(m0 + r) * 64 + k]);
        }
        #pragma unroll
        for (int i = 0; i < 32; ++i) {      // B: W_dec[k][n] -> Bsm[n][k] bf16
            int flat = t + 256 * i;
            int k = flat >> 7, n = flat & 127;
            Bsm[n][k] = f2bf(W_dec[(size_t)k * ATT + n1 + n]);
        }
        __syncthreads();

        floatx4 acc[4][2];
        #pragma unroll
        for (int mt = 0; mt < 4; ++mt)
            #pragma unroll
            for (int nt = 0; nt < 2; ++nt) acc[mt][nt] = (floatx4){0.f, 0.f, 0.f, 0.f};

        #pragma unroll
        for (int ks = 0; ks < 64; ks += 32) {
            short8 af[4], bfr[2];
            #pragma unroll
            for (int mt = 0; mt < 4; ++mt)
                af[mt] = *(const short8*)&Asm[mt * 16 + lm][ks + q * 8];
            #pragma unroll
            for (int nt = 0; nt < 2; ++nt)
                bfr[nt] = *(const short8*)&Bsm[w * 32 + nt * 16 + lm][ks + q * 8];
            #pragma unroll
            for (int mt = 0; mt < 4; ++mt)
                #pragma unroll
                for (int nt = 0; nt < 2; ++nt)
                    acc[mt][nt] = __builtin_amdgcn_mfma_f32_16x16x32_bf16(af[mt], bfr[nt], acc[mt][nt], 0, 0, 0);
        }

        float part[4][4];
        #pragma unroll
        for (int mt = 0; mt < 4; ++mt)
            #pragma unroll
            for (int r = 0; r < 4; ++r) part[mt][r] = 0.f;

        #pragma unroll
        for (int nt = 0; nt < 2; ++nt) {
            int col = n1 + w * 32 + nt * 16 + lm;
            float bcol = b_dec[col] + b_enc[col];
            float wf = w_full[col];
            #pragma unroll
            for (int mt = 0; mt < 4; ++mt)
                #pragma unroll
                for (int r = 0; r < 4; ++r) {
                    int row = m0 + mt * 16 + q * 4 + r;
                    float v = acc[mt][nt][r] + bcol;
                    dec_r[(size_t)row * ATT + col] = v;
                    part[mt][r] += fmaxf(v, 0.f) * wf;
                }
        }
        #pragma unroll
        for (int mt = 0; mt < 4; ++mt)
            #pragma unroll
            for (int r = 0; r < 4; ++r) {
                float v = part[mt][r];
                v += __shfl_xor(v, 1); v += __shfl_xor(v, 2);
                v += __shfl_xor(v, 4); v += __shfl_xor(v, 8);
                part[mt][r] = v;
            }
        if (lm == 0) {
            int sp = (idx >> 5) * 4 + w;   // 0..31
            #pragma unroll
            for (int mt = 0; mt < 4; ++mt)
                #pragma unroll
                for (int r = 0; r < 4; ++r)
                    s_part[(size_t)sp * 2048 + m0 + mt * 16 + q * 4 + r] = part[mt][r];
        }
    } else if (blk <= 768) {
        // ---- social pooling: wave wv handles anchor b = (blk-257)*4+wv ----
        int wv = t >> 6, lane = t & 63;
        int b = (blk - 257) * 4 + wv;
        int s = b >> 6, i = b & 63;
        const float* pseq = end_pos + (size_t)s * P * 2;
        const float* hrow = h + (size_t)s * P * H_DIM;

        float2 pj = ((const float2*)pseq)[lane];
        float ax = __shfl(pj.x, i), ay = __shfl(pj.y, i);
        float tlx = ax - 1.f, tly = ay + 1.f, brx = ax + 1.f, bry = ay - 1.f;
        bool oob = (pj.x >= brx) || (pj.x <= tlx) || (pj.y >= tly) || (pj.y <= bry) || (lane == i);
        int cx = (int)floorf((pj.x - tlx) * 4.0f);
        int cy = (int)floorf((tly - pj.y) * 4.0f);
        int g = cx + cy * 8;

        unsigned long long hitmask = __ballot(!oob);
        unsigned long long m = hitmask, cellmask = 0ull;
        while (m) {
            int j = __builtin_ctzll(m); m &= m - 1;
            int gj = __shfl(g, j);
            cellmask |= 1ull << gj;
        }
        int n_nz = __popcll(cellmask);
        if (lane == 0) nzS[wv] = n_nz;

        __syncthreads();
        if (t == 0) {
            while (__hip_atomic_load(flag, __ATOMIC_ACQUIRE, __HIP_MEMORY_SCOPE_AGENT) != MAGICF) {}
            int n0 = nzS[0], n1 = nzS[1], n2 = nzS[2], n3 = nzS[3];
            int base = atomicAdd(counter, n0 + n1 + n2 + n3);
            baseSh[0] = base;
            baseSh[1] = base + n0;
            baseSh[2] = base + n0 + n1;
            baseSh[3] = base + n0 + n1 + n2;
        }
        __syncthreads();
        int base = baseSh[wv];
        if (lane == 0) { cntA[b] = n_nz; baseA[b] = base; }

        unsigned long long cm = cellmask;
        int slot = 0;
        while (cm) {
            int gg = __builtin_ctzll(cm); cm &= cm - 1;
            unsigned long long jm = __ballot((!oob) && (g == gg));
            float sum = 0.f;
            while (jm) {
                int j = __builtin_ctzll(jm); jm &= jm - 1;
                sum += hrow[j * H_DIM + lane];
            }
            enc[((size_t)(b * G + gg)) * H_DIM + lane] = f2bf(sum);
            if (lane == 0) rowidx[base + slot] = b * G + gg;
            ++slot;
        }
    } else if (blk <= 784) {
        // ---- Wte[n][k] = bf16(W_enc[k][n]) ----
        float (*tileT)[65] = (float(*)[65])sm1;
        int n0 = (blk - 769) * 64;
        #pragma unroll
        for (int idx = 0; idx < 16; ++idx) {
            int flat = t + 256 * idx;
            int k = flat >> 6, c = flat & 63;
            tileT[k][c] = W_enc[(size_t)k * ATT + n0 + c];
        }
        __syncthreads();
        #pragma unroll
        for (int idx = 0; idx < 16; ++idx) {
            int flat = t + 256 * idx;
            int n = flat >> 6, k = flat & 63;
            Wte[(size_t)(n0 + n) * 64 + k] = f2bf(tileT[k][n]);
        }
    } else if (blk <= 800) {
        // ---- Wot[n][k] = bf16(W_out[k][n]) for k<68 else 0, layout 1024x96 ----
        int n0 = (blk - 785) * 64;
        int n = t & 63, kg = t >> 6;
        #pragma unroll
        for (int kk = 0; kk < 24; ++kk) {
            int k = kg * 24 + kk;
            float v = (k < 68) ? W_out[(size_t)k * ATT + n0 + n] : 0.f;
            Wot[(size_t)(n0 + n) * 96 + k] = f2bf(v);
        }
    } else {
        // ---- Wt[n][k] = bf16(W_mlp[k][n]), 1024x1024 in 64x64 tiles ----
        float (*tileT)[65] = (float(*)[65])sm1;
        int idx2 = blk - 801;
        int k0 = (idx2 & 15) * 64, n0 = (idx2 >> 4) * 64;
        #pragma unroll
        for (int idx = 0; idx < 16; ++idx) {
            int flat = t + 256 * idx;
            int r = flat >> 6, c = flat & 63;
            tileT[r][c] = W_mlp[(size_t)(k0 + r) * ATT + n0 + c];
        }
        __syncthreads();
        #pragma unroll
        for (int idx = 0; idx < 16; ++idx) {
            int flat = t + 256 * idx;
            int r = flat >> 6, c = flat & 63;
            Wt[(size_t)(n0 + r) * ATT + k0 + c] = f2bf(tileT[c][r]);
        }
    }
}

// ---------------- K2: scores over compact rows (MFMA bf16) ----------------
__global__ __launch_bounds__(256) void scoresC_mfma_kernel(const ushort* __restrict__ enc,
                                                           const int* __restrict__ rowidx,
                                                           const int* __restrict__ counter,
                                                           const float* __restrict__ dec_r,
                                                           const ushort* __restrict__ Wte,
                                                           const float* __restrict__ w_full,
                                                           const float* __restrict__ b_full,
                                                           float* __restrict__ score_c) {
    int M = counter[0];
    int row0 = blockIdx.x * 64;
    if (row0 >= M) return;
    int t = threadIdx.x;
    int w = t >> 6, lane = t & 63;
    int lm = lane & 15, q = lane >> 4;

    __shared__ __align__(16) ushort AS[64][72];    // enc rows [m][k]
    __shared__ __align__(16) ushort BS[256][72];   // W_enc^T chunk [n][k]
    __shared__ int rowS[64];
    __shared__ float redS[4][64];

    if (t < 64) rowS[t] = (row0 + t < M) ? rowidx[row0 + t] : 0;
    __syncthreads();
    #pragma unroll
    for (int i = 0; i < 4; ++i) {
        int flat = t + 256 * i;
        int r = flat >> 4, c4 = (flat & 15) * 4;
        *(uint2*)&AS[r][c4] = *(const uint2*)&enc[(size_t)rowS[r] * 64 + c4];
    }
    int bbr[16];
    #pragma unroll
    for (int mt = 0; mt < 4; ++mt)
        #pragma unroll
        for (int r = 0; r < 4; ++r)
            bbr[mt * 4 + r] = rowS[mt * 16 + q * 4 + r] >> 6;

    float part[4][4];
    #pragma unroll
    for (int mt = 0; mt < 4; ++mt)
        #pragma unroll
        for (int r = 0; r < 4; ++r) part[mt][r] = 0.f;

    for (int c = 0; c < 4; ++c) {
        __syncthreads();
        #pragma unroll
        for (int i = 0; i < 16; ++i) {
            int flat = t + 256 * i;
            int r = flat >> 4, c4 = (flat & 15) * 4;
            *(uint2*)&BS[r][c4] = *(const uint2*)&Wte[(size_t)(c * 256 + r) * 64 + c4];
        }
        __syncthreads();

        floatx4 acc[4][4];
        #pragma unroll
        for (int mt = 0; mt < 4; ++mt)
            #pragma unroll
            for (int nt = 0; nt < 4; ++nt) acc[mt][nt] = (floatx4){0.f, 0.f, 0.f, 0.f};

        #pragma unroll
        for (int ks = 0; ks < 64; ks += 32) {
            short8 af[4], bfr[4];
            #pragma unroll
            for (int mt = 0; mt < 4; ++mt)
                af[mt] = *(const short8*)&AS[mt * 16 + lm][ks + q * 8];
            #pragma unroll
            for (int nt = 0; nt < 4; ++nt)
                bfr[nt] = *(const short8*)&BS[w * 64 + nt * 16 + lm][ks + q * 8];
            #pragma unroll
            for (int mt = 0; mt < 4; ++mt)
                #pragma unroll
                for (int nt = 0; nt < 4; ++nt)
                    acc[mt][nt] = __builtin_amdgcn_mfma_f32_16x16x32_bf16(af[mt], bfr[nt], acc[mt][nt], 0, 0, 0);
        }

        int colbase = c * 256 + w * 64;
        #pragma unroll
        for (int nt = 0; nt < 4; ++nt) {
            int col = colbase + nt * 16 + lm;
            float wf = w_full[col];
            #pragma unroll
            for (int mt = 0; mt < 4; ++mt)
                #pragma unroll
                for (int r = 0; r < 4; ++r) {
                    float v = acc[mt][nt][r] + dec_r[(size_t)bbr[mt * 4 + r] * ATT + col];
                    part[mt][r] += fmaxf(v, 0.f) * wf;
                }
        }
    }
    #pragma unroll
    for (int mt = 0; mt < 4; ++mt)
        #pragma unroll
        for (int r = 0; r < 4; ++r) {
            float v = part[mt][r];
            v += __shfl_xor(v, 1); v += __shfl_xor(v, 2);
            v += __shfl_xor(v, 4); v += __shfl_xor(v, 8);
            part[mt][r] = v;
        }
    if (lm == 0) {
        #pragma unroll
        for (int mt = 0; mt < 4; ++mt)
            #pragma unroll
            for (int r = 0; r < 4; ++r)
                redS[w][mt * 16 + q * 4 + r] = part[mt][r];
    }
    __syncthreads();
    if (t < 64) {
        int row = row0 + t;
        if (row < M)
            score_c[row] = redS[0][t] + redS[1][t] + redS[2][t] + redS[3][t] + b_full[0];
    }
}

// ---------------- K3: softmax + ctx + emb -> ctx_bf[2048][96] ----------------
__global__ __launch_bounds__(64) void softmax_ctx_kernel(const float* __restrict__ score_c,
                                                         const int* __restrict__ rowidx,
                                                         const int* __restrict__ cntA,
                                                         const int* __restrict__ baseA,
                                                         const float* __restrict__ s_part,
                                                         const ushort* __restrict__ enc,
                                                         const float* __restrict__ end_pos,
                                                         const float* __restrict__ rel_pos,
                                                         const float* __restrict__ W_embed,
                                                         const float* __restrict__ b_embed,
                                                         const float* __restrict__ b_full,
                                                         ushort* __restrict__ ctx_bf) {
    int b = blockIdx.x, t = threadIdx.x;
    int cnt = cntA[b], base = baseA[b];
    float sp = (t < 32) ? s_part[(size_t)t * 2048 + b] : 0.f;
    #pragma unroll
    for (int o = 32; o > 0; o >>= 1) sp += __shfl_xor(sp, o);
    float se = sp + b_full[0];
    float sc = se;
    int ri = 0;
    if (t < cnt) { sc = score_c[base + t]; ri = rowidx[base + t]; }
    float mx = sc;
    #pragma unroll
    for (int o = 32; o > 0; o >>= 1) mx = fmaxf(mx, __shfl_xor(mx, o));
    float e = expf(sc - mx);
    float ssum = e;
    #pragma unroll
    for (int o = 32; o > 0; o >>= 1) ssum += __shfl_xor(ssum, o);
    __shared__ float aS[G];
    __shared__ int rS[G];
    aS[t] = e / ssum;
    rS[t] = ri;
    __syncthreads();
    float ctx = 0.f;
    for (int i = 0; i < cnt; ++i)
        ctx += aS[i] * bf2f(enc[(size_t)rS[i] * H_DIM + t]);
    ctx_bf[(size_t)b * 96 + t] = f2bf(ctx);
    if (t < EMB) {
        float e0 = end_pos[2*b], e1 = end_pos[2*b+1], e2 = rel_pos[2*b], e3 = rel_pos[2*b+1];
        float v = b_embed[t] + e0 * W_embed[0*EMB + t] + e1 * W_embed[1*EMB + t]
                             + e2 * W_embed[2*EMB + t] + e3 * W_embed[3*EMB + t];
        ctx_bf[(size_t)b * 96 + 64 + t] = f2bf(v > 0.f ? v : 0.f);
    }
    if (t < 28) ctx_bf[(size_t)b * 96 + 68 + t] = 0;
}

// ---------------- K4: persistent out -> barrier -> mlp -> barrier -> bn ----------------
__global__ __launch_bounds__(256, 2) void tail_kernel(const ushort* __restrict__ ctx_bf,  // [2048][96]
                                                      const ushort* __restrict__ Wot,     // [1024][96]
                                                      const float* __restrict__ b_out,
                                                      const ushort* __restrict__ Wt,      // [1024][1024]
                                                      const float* __restrict__ b_mlp,
                                                      const float* __restrict__ gamma,
                                                      const float* __restrict__ beta,
                                                      ushort* __restrict__ out_bf,        // [2048][1024]
                                                      float* __restrict__ X,              // [2048][1024]
                                                      float* __restrict__ sums,
                                                      int* __restrict__ bar,
                                                      float* __restrict__ dout) {
    __shared__ __align__(16) char SM[26624];
    int t = threadIdx.x, blk = blockIdx.x;
    int w = t >> 6, lane = t & 63;
    int lm = lane & 15, q = lane >> 4;

    // ===== phase O: out tile 64x64, K=96 =====
    {
        ushort (*Asm)[104] = (ushort(*)[104])SM;
        ushort (*Bsm)[104] = (ushort(*)[104])(SM + 13312);
        int m0 = (blk & 31) * 64, n0 = (blk >> 5) * 64;
        {
            int r = t >> 2, pp = t & 3;
            #pragma unroll
            for (int ii = 0; ii < 3; ++ii) {
                int c8 = (pp * 3 + ii) * 8;
                *(uint4*)&Asm[r][c8] = *(const uint4*)&ctx_bf[(size_t)(m0 + r) * 96 + c8];
                *(uint4*)&Bsm[r][c8] = *(const uint4*)&Wot[(size_t)(n0 + r) * 96 + c8];
            }
        }
        __syncthreads();
        floatx4 acc[4];
        #pragma unroll
        for (int mt = 0; mt < 4; ++mt) acc[mt] = (floatx4){0.f, 0.f, 0.f, 0.f};
        #pragma unroll
        for (int ks = 0; ks < 96; ks += 32) {
            short8 af[4], bfr;
            #pragma unroll
            for (int mt = 0; mt < 4; ++mt)
                af[mt] = *(const short8*)&Asm[mt * 16 + lm][ks + q * 8];
            bfr = *(const short8*)&Bsm[w * 16 + lm][ks + q * 8];
            #pragma unroll
            for (int mt = 0; mt < 4; ++mt)
                acc[mt] = __builtin_amdgcn_mfma_f32_16x16x32_bf16(af[mt], bfr, acc[mt], 0, 0, 0);
        }
        __syncthreads();   // done reading LDS; reuse for staging
        ushort (*St)[64] = (ushort(*)[64])SM;
        int colL = w * 16 + lm;
        float bv = b_out[n0 + colL];
        #pragma unroll
        for (int mt = 0; mt < 4; ++mt)
            #pragma unroll
            for (int r = 0; r < 4; ++r)
                St[mt * 16 + q * 4 + r][colL] = f2bf(fmaxf(acc[mt][r] + bv, 0.f));
        __syncthreads();
        // device-coherent stores (agent scope): 2048 uints
        #pragma unroll
        for (int i = 0; i < 8; ++i) {
            int flat = t + 256 * i;
            int r = flat >> 5, c2 = (flat & 31) * 2;
            unsigned val = (unsigned)St[r][c2] | ((unsigned)St[r][c2 + 1] << 16);
            __hip_atomic_store((unsigned*)&out_bf[(size_t)(m0 + r) * ATT + n0 + c2], val,
                               __ATOMIC_RELAXED, __HIP_MEMORY_SCOPE_AGENT);
        }
    }
    grid_barrier(&bar[0]);

    // ===== phase M: mlp tile 64x64, K=1024 + BN stats =====
    {
        ushort (*Asm)[72] = (ushort(*)[72])SM;
        ushort (*Bsm)[72] = (ushort(*)[72])(SM + 9216);
        int m0 = (blk & 31) * 64, n0 = (blk >> 5) * 64;
        floatx4 acc[4];
        #pragma unroll
        for (int mt = 0; mt < 4; ++mt) acc[mt] = (floatx4){0.f, 0.f, 0.f, 0.f};

        for (int k0 = 0; k0 < 1024; k0 += 64) {
            __syncthreads();
            #pragma unroll
            for (int i = 0; i < 4; ++i) {
                int flat = t + 256 * i;
                int r = flat >> 4, c4 = (flat & 15) * 4;
                *(uint2*)&Asm[r][c4] = *(const uint2*)&out_bf[(size_t)(m0 + r) * ATT + k0 + c4];
                *(uint2*)&Bsm[r][c4] = *(const uint2*)&Wt[(size_t)(n0 + r) * ATT + k0 + c4];
            }
            __syncthreads();
            #pragma unroll
            for (int ks = 0; ks < 64; ks += 32) {
                short8 af[4], bfr;
                #pragma unroll
                for (int mt = 0; mt < 4; ++mt)
                    af[mt] = *(const short8*)&Asm[mt * 16 + lm][ks + q * 8];
                bfr = *(const short8*)&Bsm[w * 16 + lm][ks + q * 8];
                #pragma unroll
                for (int mt = 0; mt < 4; ++mt)
                    acc[mt] = __builtin_amdgcn_mfma_f32_16x16x32_bf16(af[mt], bfr, acc[mt], 0, 0, 0);
            }
        }
        int col = n0 + w * 16 + lm;
        float bv = b_mlp[col];
        float s1 = 0.f, s2 = 0.f;
        #pragma unroll
        for (int mt = 0; mt < 4; ++mt)
            #pragma unroll
            for (int r = 0; r < 4; ++r) {
                int row = m0 + mt * 16 + q * 4 + r;
                float v = acc[mt][r] + bv;
                __hip_atomic_store(&X[(size_t)row * ATT + col], v,
                                   __ATOMIC_RELAXED, __HIP_MEMORY_SCOPE_AGENT);
                s1 += v; s2 += v * v;
            }
        s1 += __shfl_xor(s1, 16); s1 += __shfl_xor(s1, 32);
        s2 += __shfl_xor(s2, 16); s2 += __shfl_xor(s2, 32);
        if (q == 0) {
            atomicAdd(&sums[col], s1);
            atomicAdd(&sums[ATT + col], s2);
        }
    }
    grid_barrier(&bar[16]);

    // ===== phase B: bn (float4), 512 blocks x 4 chunks =====
    #pragma unroll
    for (int it = 0; it < 4; ++it) {
        size_t i4 = ((size_t)blk * 1024 + it * 256 + t) * 4;
        int f = (int)(i4 & 1023);
        float4 xv = *(const float4*)&X[i4];
        float4 s1 = *(const float4*)&sums[f];
        float4 s2 = *(const float4*)&sums[ATT + f];
        float4 gm = *(const float4*)&gamma[f];
        float4 bt = *(const float4*)&beta[f];
        float4 ov;
        float mu, var, v;
        mu = s1.x * (1.f / BB); var = s2.x * (1.f / BB) - mu * mu;
        v = (xv.x - mu) * rsqrtf(var + 1e-5f) * gm.x + bt.x; ov.x = v > 0.f ? v : 0.f;
        mu = s1.y * (1.f / BB); var = s2.y * (1.f / BB) - mu * mu;
        v = (xv.y - mu) * rsqrtf(var + 1e-5f) * gm.y + bt.y; ov.y = v > 0.f ? v : 0.f;
        mu = s1.z * (1.f / BB); var = s2.z * (1.f / BB) - mu * mu;
        v = (xv.z - mu) * rsqrtf(var + 1e-5f) * gm.z + bt.z; ov.z = v > 0.f ? v : 0.f;
        mu = s1.w * (1.f / BB); var = s2.w * (1.f / BB) - mu * mu;
        v = (xv.w - mu) * rsqrtf(var + 1e-5f) * gm.w + bt.w; ov.w = v > 0.f ? v : 0.f;
        *(float4*)&dout[i4] = ov;
    }
}

extern "C" void kernel_launch(void* const* d_in, const int* in_sizes, int n_in,
                              void* d_out, int out_size, void* d_ws, size_t ws_size,
                              hipStream_t stream) {
    const float* h        = (const float*)d_in[0];
    const float* end_pos  = (const float*)d_in[2];
    const float* rel_pos  = (const float*)d_in[3];
    const float* W_enc    = (const float*)d_in[4];
    const float* b_enc    = (const float*)d_in[5];
    const float* W_dec    = (const float*)d_in[6];
    const float* b_dec    = (const float*)d_in[7];
    const float* w_full   = (const float*)d_in[8];
    const float* b_full   = (const float*)d_in[9];
    const float* W_embed  = (const float*)d_in[10];
    const float* b_embed  = (const float*)d_in[11];
    const float* W_out    = (const float*)d_in[12];
    const float* b_out    = (const float*)d_in[13];
    const float* W_mlp    = (const float*)d_in[14];
    const float* b_mlp    = (const float*)d_in[15];
    const float* bn_gamma = (const float*)d_in[16];
    const float* bn_beta  = (const float*)d_in[17];

    float* ws = (float*)d_ws;
    ushort* enc     = (ushort*)ws;                 // 131072 x 64 bf16
    ushort* Wte     = (ushort*)(ws + 4259840);     // 1024 x 64 bf16
    ushort* Wot     = (ushort*)(ws + 4325376);     // 1024 x 96 bf16
    ushort* Wt      = (ushort*)(ws + 4374528);     // 1024 x 1024 bf16
    ushort* ctx_bf  = (ushort*)(ws + 4898816);     // 2048 x 96 bf16
    ushort* out_bf  = (ushort*)(ws + 4997120);     // 2048 x 1024 bf16
    float*  x       = ws + 6045696;                // 2048 x 1024 fp32
    float*  dec_r   = ws + 8388608;                // 2048 x 1024 fp32
    int*    rowidx  = (int*)(ws + 10485760);       // 131,072
    float*  score_c = ws + 10616832;               // 131,072
    int*    cntA    = (int*)(ws + 10747904);       // 2,048
    int*    baseA   = (int*)(ws + 10749952);       // 2,048
    int*    counter = (int*)(ws + 10752000);       // 64
    float*  sums    = ws + 10752064;               // 2,048
    float*  s_part  = ws + 10754112;               // 32 x 2048
    int*    flag    = (int*)(ws + 10819648);       // 64
    int*    bar     = (int*)(ws + 10819712);       // 64

    prep_kernel<<<K1_BLOCKS, 256, 0, stream>>>(h, end_pos, W_enc, W_dec, W_out, W_mlp,
                                               b_dec, b_enc, w_full,
                                               enc, Wte, Wot, Wt, dec_r, s_part,
                                               rowidx, cntA, baseA, counter, sums, bar, flag);
    scoresC_mfma_kernel<<<MAXROWS / 64, 256, 0, stream>>>(enc, rowidx, counter, dec_r, Wte,
                                                          w_full, b_full, score_c);
    softmax_ctx_kernel<<<BB, 64, 0, stream>>>(score_c, rowidx, cntA, baseA, s_part, enc,
                                              end_pos, rel_pos, W_embed, b_embed, b_full, ctx_bf);
    tail_kernel<<<TAIL_BLOCKS, 256, 0, stream>>>(ctx_bf, Wot, b_out, Wt, b_mlp,
                                                 bn_gamma, bn_beta,
                                                 out_bf, x, sums, bar, (float*)d_out);
}

// Round 9
// 163.614 us; speedup vs baseline: 1.4457x; 1.4457x over previous
//
#include <hip/hip_runtime.h>
#include <hip/hip_bf16.h>
#include <math.h>

#define H_DIM 64
#define G 64
#define ATT 1024
#define EMB 4
#define P 64
#define BB 2048   // batch B = S*P
#define MAXROWS 129088  // 2048*63 rounded up to multiple of 64
#define K1_BLOCKS 1057  // 1 init + 256 dec + 512 pool + 16 Wte + 16 Wot + 256 Wt
#define MAGICF 0x13579BDF

typedef __attribute__((ext_vector_type(8))) short short8;
typedef __attribute__((ext_vector_type(4))) float floatx4;

__device__ inline ushort f2bf(float v) {
    __hip_bfloat16 b = __float2bfloat16(v);
    return *(ushort*)&b;
}
__device__ inline float bf2f(ushort u) {
    union { float f; unsigned u32; } x;
    x.u32 = ((unsigned)u) << 16;
    return x.f;
}

// ---------------- K1: init | dec(MFMA, self-contained) | pool | W_enc^T | W_out^T(pad96) | W_mlp^T ----------------
__global__ __launch_bounds__(256) void prep_kernel(const float* __restrict__ h,
                                                   const float* __restrict__ end_pos,
                                                   const float* __restrict__ W_enc,
                                                   const float* __restrict__ W_dec,
                                                   const float* __restrict__ W_out,
                                                   const float* __restrict__ W_mlp,
                                                   const float* __restrict__ b_dec,
                                                   const float* __restrict__ b_enc,
                                                   const float* __restrict__ w_full,
                                                   ushort* __restrict__ enc,
                                                   ushort* __restrict__ Wte,
                                                   ushort* __restrict__ Wot,
                                                   ushort* __restrict__ Wt,
                                                   float* __restrict__ dec_r,
                                                   float* __restrict__ s_part,
                                                   int* __restrict__ rowidx,
                                                   int* __restrict__ cntA,
                                                   int* __restrict__ baseA,
                                                   int* __restrict__ counter,
                                                   float* __restrict__ sums,
                                                   int* __restrict__ flag) {
    __shared__ __align__(16) char sm1[28672];
    __shared__ int nzS[4], baseSh[4];

    int blk = blockIdx.x;
    int t = threadIdx.x;

    if (blk == 0) {
        // ---- init: zero counter + sums; publish flag ----
        if (t < 64) __hip_atomic_store(&counter[t], 0, __ATOMIC_RELAXED, __HIP_MEMORY_SCOPE_AGENT);
        int* sz = (int*)sums;
        for (int i = t; i < 2048; i += 256)
            __hip_atomic_store(&sz[i], 0, __ATOMIC_RELAXED, __HIP_MEMORY_SCOPE_AGENT);
        __syncthreads();
        if (t == 0) __hip_atomic_store(flag, MAGICF, __ATOMIC_RELEASE, __HIP_MEMORY_SCOPE_AGENT);
    } else if (blk <= 256) {
        // ---- dec: self-contained MFMA tile 64 rows x 128 cols, K=64 ----
        int idx = blk - 1;                  // 0..255
        int m0 = (idx & 31) * 64, n1 = (idx >> 5) * 128;
        int w = t >> 6, lane = t & 63;
        int lm = lane & 15, q = lane >> 4;
        ushort (*Asm)[72] = (ushort(*)[72])sm1;                 // 64x72
        ushort (*Bsm)[72] = (ushort(*)[72])(sm1 + 9216);        // 128x72

        #pragma unroll
        for (int i = 0; i < 16; ++i) {      // A: h fp32 -> bf16, 64x64
            int flat = t + 256 * i;
            int r = flat >> 6, k = flat & 63;
            Asm[r][k] = f2bf(h[(size_t)(m0 + r) * 64 + k]);
        }
        #pragma unroll
        for (int i = 0; i < 32; ++i) {      // B: W_dec[k][n] -> Bsm[n][k] bf16
            int flat = t + 256 * i;
            int k = flat >> 7, n = flat & 127;
            Bsm[n][k] = f2bf(W_dec[(size_t)k * ATT + n1 + n]);
        }
        __syncthreads();

        floatx4 acc[4][2];
        #pragma unroll
        for (int mt = 0; mt < 4; ++mt)
            #pragma unroll
            for (int nt = 0; nt < 2; ++nt) acc[mt][nt] = (floatx4){0.f, 0.f, 0.f, 0.f};

        #pragma unroll
        for (int ks = 0; ks < 64; ks += 32) {
            short8 af[4], bfr[2];
            #pragma unroll
            for (int mt = 0; mt < 4; ++mt)
                af[mt] = *(const short8*)&Asm[mt * 16 + lm][ks + q * 8];
            #pragma unroll
            for (int nt = 0; nt < 2; ++nt)
                bfr[nt] = *(const short8*)&Bsm[w * 32 + nt * 16 + lm][ks + q * 8];
            #pragma unroll
            for (int mt = 0; mt < 4; ++mt)
                #pragma unroll
                for (int nt = 0; nt < 2; ++nt)
                    acc[mt][nt] = __builtin_amdgcn_mfma_f32_16x16x32_bf16(af[mt], bfr[nt], acc[mt][nt], 0, 0, 0);
        }

        float part[4][4];
        #pragma unroll
        for (int mt = 0; mt < 4; ++mt)
            #pragma unroll
            for (int r = 0; r < 4; ++r) part[mt][r] = 0.f;

        #pragma unroll
        for (int nt = 0; nt < 2; ++nt) {
            int col = n1 + w * 32 + nt * 16 + lm;
            float bcol = b_dec[col] + b_enc[col];
            float wf = w_full[col];
            #pragma unroll
            for (int mt = 0; mt < 4; ++mt)
                #pragma unroll
                for (int r = 0; r < 4; ++r) {
                    int row = m0 + mt * 16 + q * 4 + r;
                    float v = acc[mt][nt][r] + bcol;
                    dec_r[(size_t)row * ATT + col] = v;
                    part[mt][r] += fmaxf(v, 0.f) * wf;
                }
        }
        #pragma unroll
        for (int mt = 0; mt < 4; ++mt)
            #pragma unroll
            for (int r = 0; r < 4; ++r) {
                float v = part[mt][r];
                v += __shfl_xor(v, 1); v += __shfl_xor(v, 2);
                v += __shfl_xor(v, 4); v += __shfl_xor(v, 8);
                part[mt][r] = v;
            }
        if (lm == 0) {
            int sp = (idx >> 5) * 4 + w;   // 0..31
            #pragma unroll
            for (int mt = 0; mt < 4; ++mt)
                #pragma unroll
                for (int r = 0; r < 4; ++r)
                    s_part[(size_t)sp * 2048 + m0 + mt * 16 + q * 4 + r] = part[mt][r];
        }
    } else if (blk <= 768) {
        // ---- social pooling: wave wv handles anchor b = (blk-257)*4+wv ----
        int wv = t >> 6, lane = t & 63;
        int b = (blk - 257) * 4 + wv;
        int s = b >> 6, i = b & 63;
        const float* pseq = end_pos + (size_t)s * P * 2;
        const float* hrow = h + (size_t)s * P * H_DIM;

        float2 pj = ((const float2*)pseq)[lane];
        float ax = __shfl(pj.x, i), ay = __shfl(pj.y, i);
        float tlx = ax - 1.f, tly = ay + 1.f, brx = ax + 1.f, bry = ay - 1.f;
        bool oob = (pj.x >= brx) || (pj.x <= tlx) || (pj.y >= tly) || (pj.y <= bry) || (lane == i);
        int cx = (int)floorf((pj.x - tlx) * 4.0f);
        int cy = (int)floorf((tly - pj.y) * 4.0f);
        int g = cx + cy * 8;

        unsigned long long hitmask = __ballot(!oob);
        unsigned long long m = hitmask, cellmask = 0ull;
        while (m) {
            int j = __builtin_ctzll(m); m &= m - 1;
            int gj = __shfl(g, j);
            cellmask |= 1ull << gj;
        }
        int n_nz = __popcll(cellmask);
        if (lane == 0) nzS[wv] = n_nz;

        __syncthreads();
        if (t == 0) {
            while (__hip_atomic_load(flag, __ATOMIC_ACQUIRE, __HIP_MEMORY_SCOPE_AGENT) != MAGICF) {}
            int n0 = nzS[0], n1 = nzS[1], n2 = nzS[2], n3 = nzS[3];
            int base = atomicAdd(counter, n0 + n1 + n2 + n3);
            baseSh[0] = base;
            baseSh[1] = base + n0;
            baseSh[2] = base + n0 + n1;
            baseSh[3] = base + n0 + n1 + n2;
        }
        __syncthreads();
        int base = baseSh[wv];
        if (lane == 0) { cntA[b] = n_nz; baseA[b] = base; }

        unsigned long long cm = cellmask;
        int slot = 0;
        while (cm) {
            int gg = __builtin_ctzll(cm); cm &= cm - 1;
            unsigned long long jm = __ballot((!oob) && (g == gg));
            float sum = 0.f;
            while (jm) {
                int j = __builtin_ctzll(jm); jm &= jm - 1;
                sum += hrow[j * H_DIM + lane];
            }
            enc[((size_t)(b * G + gg)) * H_DIM + lane] = f2bf(sum);
            if (lane == 0) rowidx[base + slot] = b * G + gg;
            ++slot;
        }
    } else if (blk <= 784) {
        // ---- Wte[n][k] = bf16(W_enc[k][n]) ----
        float (*tileT)[65] = (float(*)[65])sm1;
        int n0 = (blk - 769) * 64;
        #pragma unroll
        for (int idx = 0; idx < 16; ++idx) {
            int flat = t + 256 * idx;
            int k = flat >> 6, c = flat & 63;
            tileT[k][c] = W_enc[(size_t)k * ATT + n0 + c];
        }
        __syncthreads();
        #pragma unroll
        for (int idx = 0; idx < 16; ++idx) {
            int flat = t + 256 * idx;
            int n = flat >> 6, k = flat & 63;
            Wte[(size_t)(n0 + n) * 64 + k] = f2bf(tileT[k][n]);
        }
    } else if (blk <= 800) {
        // ---- Wot[n][k] = bf16(W_out[k][n]) for k<68 else 0, layout 1024x96 ----
        int n0 = (blk - 785) * 64;
        int n = t & 63, kg = t >> 6;
        #pragma unroll
        for (int kk = 0; kk < 24; ++kk) {
            int k = kg * 24 + kk;
            float v = (k < 68) ? W_out[(size_t)k * ATT + n0 + n] : 0.f;
            Wot[(size_t)(n0 + n) * 96 + k] = f2bf(v);
        }
    } else {
        // ---- Wt[n][k] = bf16(W_mlp[k][n]), 1024x1024 in 64x64 tiles ----
        float (*tileT)[65] = (float(*)[65])sm1;
        int idx2 = blk - 801;
        int k0 = (idx2 & 15) * 64, n0 = (idx2 >> 4) * 64;
        #pragma unroll
        for (int idx = 0; idx < 16; ++idx) {
            int flat = t + 256 * idx;
            int r = flat >> 6, c = flat & 63;
            tileT[r][c] = W_mlp[(size_t)(k0 + r) * ATT + n0 + c];
        }
        __syncthreads();
        #pragma unroll
        for (int idx = 0; idx < 16; ++idx) {
            int flat = t + 256 * idx;
            int r = flat >> 6, c = flat & 63;
            Wt[(size_t)(n0 + r) * ATT + k0 + c] = f2bf(tileT[c][r]);
        }
    }
}

// ---------------- K2: scores over compact rows (MFMA bf16) ----------------
__global__ __launch_bounds__(256) void scoresC_mfma_kernel(const ushort* __restrict__ enc,
                                                           const int* __restrict__ rowidx,
                                                           const int* __restrict__ counter,
                                                           const float* __restrict__ dec_r,
                                                           const ushort* __restrict__ Wte,
                                                           const float* __restrict__ w_full,
                                                           const float* __restrict__ b_full,
                                                           float* __restrict__ score_c) {
    int M = counter[0];
    int row0 = blockIdx.x * 64;
    if (row0 >= M) return;
    int t = threadIdx.x;
    int w = t >> 6, lane = t & 63;
    int lm = lane & 15, q = lane >> 4;

    __shared__ __align__(16) ushort AS[64][72];    // enc rows [m][k]
    __shared__ __align__(16) ushort BS[256][72];   // W_enc^T chunk [n][k]
    __shared__ int rowS[64];
    __shared__ float redS[4][64];

    if (t < 64) rowS[t] = (row0 + t < M) ? rowidx[row0 + t] : 0;
    __syncthreads();
    #pragma unroll
    for (int i = 0; i < 4; ++i) {
        int flat = t + 256 * i;
        int r = flat >> 4, c4 = (flat & 15) * 4;
        *(uint2*)&AS[r][c4] = *(const uint2*)&enc[(size_t)rowS[r] * 64 + c4];
    }
    int bbr[16];
    #pragma unroll
    for (int mt = 0; mt < 4; ++mt)
        #pragma unroll
        for (int r = 0; r < 4; ++r)
            bbr[mt * 4 + r] = rowS[mt * 16 + q * 4 + r] >> 6;

    float part[4][4];
    #pragma unroll
    for (int mt = 0; mt < 4; ++mt)
        #pragma unroll
        for (int r = 0; r < 4; ++r) part[mt][r] = 0.f;

    for (int c = 0; c < 4; ++c) {
        __syncthreads();
        #pragma unroll
        for (int i = 0; i < 16; ++i) {
            int flat = t + 256 * i;
            int r = flat >> 4, c4 = (flat & 15) * 4;
            *(uint2*)&BS[r][c4] = *(const uint2*)&Wte[(size_t)(c * 256 + r) * 64 + c4];
        }
        __syncthreads();

        floatx4 acc[4][4];
        #pragma unroll
        for (int mt = 0; mt < 4; ++mt)
            #pragma unroll
            for (int nt = 0; nt < 4; ++nt) acc[mt][nt] = (floatx4){0.f, 0.f, 0.f, 0.f};

        #pragma unroll
        for (int ks = 0; ks < 64; ks += 32) {
            short8 af[4], bfr[4];
            #pragma unroll
            for (int mt = 0; mt < 4; ++mt)
                af[mt] = *(const short8*)&AS[mt * 16 + lm][ks + q * 8];
            #pragma unroll
            for (int nt = 0; nt < 4; ++nt)
                bfr[nt] = *(const short8*)&BS[w * 64 + nt * 16 + lm][ks + q * 8];
            #pragma unroll
            for (int mt = 0; mt < 4; ++mt)
                #pragma unroll
                for (int nt = 0; nt < 4; ++nt)
                    acc[mt][nt] = __builtin_amdgcn_mfma_f32_16x16x32_bf16(af[mt], bfr[nt], acc[mt][nt], 0, 0, 0);
        }

        int colbase = c * 256 + w * 64;
        #pragma unroll
        for (int nt = 0; nt < 4; ++nt) {
            int col = colbase + nt * 16 + lm;
            float wf = w_full[col];
            #pragma unroll
            for (int mt = 0; mt < 4; ++mt)
                #pragma unroll
                for (int r = 0; r < 4; ++r) {
                    float v = acc[mt][nt][r] + dec_r[(size_t)bbr[mt * 4 + r] * ATT + col];
                    part[mt][r] += fmaxf(v, 0.f) * wf;
                }
        }
    }
    #pragma unroll
    for (int mt = 0; mt < 4; ++mt)
        #pragma unroll
        for (int r = 0; r < 4; ++r) {
            float v = part[mt][r];
            v += __shfl_xor(v, 1); v += __shfl_xor(v, 2);
            v += __shfl_xor(v, 4); v += __shfl_xor(v, 8);
            part[mt][r] = v;
        }
    if (lm == 0) {
        #pragma unroll
        for (int mt = 0; mt < 4; ++mt)
            #pragma unroll
            for (int r = 0; r < 4; ++r)
                redS[w][mt * 16 + q * 4 + r] = part[mt][r];
    }
    __syncthreads();
    if (t < 64) {
        int row = row0 + t;
        if (row < M)
            score_c[row] = redS[0][t] + redS[1][t] + redS[2][t] + redS[3][t] + b_full[0];
    }
}

// ---------------- K3: softmax + ctx + emb -> ctx_bf[2048][96] ----------------
__global__ __launch_bounds__(64) void softmax_ctx_kernel(const float* __restrict__ score_c,
                                                         const int* __restrict__ rowidx,
                                                         const int* __restrict__ cntA,
                                                         const int* __restrict__ baseA,
                                                         const float* __restrict__ s_part,
                                                         const ushort* __restrict__ enc,
                                                         const float* __restrict__ end_pos,
                                                         const float* __restrict__ rel_pos,
                                                         const float* __restrict__ W_embed,
                                                         const float* __restrict__ b_embed,
                                                         const float* __restrict__ b_full,
                                                         ushort* __restrict__ ctx_bf) {
    int b = blockIdx.x, t = threadIdx.x;
    int cnt = cntA[b], base = baseA[b];
    float sp = (t < 32) ? s_part[(size_t)t * 2048 + b] : 0.f;
    #pragma unroll
    for (int o = 32; o > 0; o >>= 1) sp += __shfl_xor(sp, o);
    float se = sp + b_full[0];
    float sc = se;
    int ri = 0;
    if (t < cnt) { sc = score_c[base + t]; ri = rowidx[base + t]; }
    float mx = sc;
    #pragma unroll
    for (int o = 32; o > 0; o >>= 1) mx = fmaxf(mx, __shfl_xor(mx, o));
    float e = expf(sc - mx);
    float ssum = e;
    #pragma unroll
    for (int o = 32; o > 0; o >>= 1) ssum += __shfl_xor(ssum, o);
    __shared__ float aS[G];
    __shared__ int rS[G];
    aS[t] = e / ssum;
    rS[t] = ri;
    __syncthreads();
    float ctx = 0.f;
    for (int i = 0; i < cnt; ++i)
        ctx += aS[i] * bf2f(enc[(size_t)rS[i] * H_DIM + t]);
    ctx_bf[(size_t)b * 96 + t] = f2bf(ctx);
    if (t < EMB) {
        float e0 = end_pos[2*b], e1 = end_pos[2*b+1], e2 = rel_pos[2*b], e3 = rel_pos[2*b+1];
        float v = b_embed[t] + e0 * W_embed[0*EMB + t] + e1 * W_embed[1*EMB + t]
                             + e2 * W_embed[2*EMB + t] + e3 * W_embed[3*EMB + t];
        ctx_bf[(size_t)b * 96 + 64 + t] = f2bf(v > 0.f ? v : 0.f);
    }
    if (t < 28) ctx_bf[(size_t)b * 96 + 68 + t] = 0;
}

// ---------------- K4: out_bf = bf16(relu(ctx_bf @ Wot^T + b_out))  (MFMA, K=96) ----------------
__global__ __launch_bounds__(256) void out_mfma_kernel(const ushort* __restrict__ A,   // ctx_bf [2048][96]
                                                       const ushort* __restrict__ Bt,  // Wot [1024][96]
                                                       const float* __restrict__ bias,
                                                       ushort* __restrict__ out) {
    int t = threadIdx.x;
    int w = t >> 6, lane = t & 63;
    int lm = lane & 15, q = lane >> 4;
    int m0 = blockIdx.x * 64, n1 = blockIdx.y * 128;
    __shared__ __align__(16) ushort Asm[64][104];
    __shared__ __align__(16) ushort Bsm[128][104];

    {
        int r = t >> 2, pp = t & 3;
        #pragma unroll
        for (int ii = 0; ii < 3; ++ii) {
            int c8 = (pp * 3 + ii) * 8;
            *(uint4*)&Asm[r][c8] = *(const uint4*)&A[(size_t)(m0 + r) * 96 + c8];
        }
    }
    {
        int r = t >> 1, pp = t & 1;
        #pragma unroll
        for (int ii = 0; ii < 6; ++ii) {
            int c8 = (pp * 6 + ii) * 8;
            *(uint4*)&Bsm[r][c8] = *(const uint4*)&Bt[(size_t)(n1 + r) * 96 + c8];
        }
    }
    __syncthreads();

    floatx4 acc[4][2];
    #pragma unroll
    for (int mt = 0; mt < 4; ++mt)
        #pragma unroll
        for (int nt = 0; nt < 2; ++nt) acc[mt][nt] = (floatx4){0.f, 0.f, 0.f, 0.f};

    #pragma unroll
    for (int ks = 0; ks < 96; ks += 32) {
        short8 af[4], bfr[2];
        #pragma unroll
        for (int mt = 0; mt < 4; ++mt)
            af[mt] = *(const short8*)&Asm[mt * 16 + lm][ks + q * 8];
        #pragma unroll
        for (int nt = 0; nt < 2; ++nt)
            bfr[nt] = *(const short8*)&Bsm[w * 32 + nt * 16 + lm][ks + q * 8];
        #pragma unroll
        for (int mt = 0; mt < 4; ++mt)
            #pragma unroll
            for (int nt = 0; nt < 2; ++nt)
                acc[mt][nt] = __builtin_amdgcn_mfma_f32_16x16x32_bf16(af[mt], bfr[nt], acc[mt][nt], 0, 0, 0);
    }
    #pragma unroll
    for (int nt = 0; nt < 2; ++nt) {
        int col = n1 + w * 32 + nt * 16 + lm;
        float bv = bias[col];
        #pragma unroll
        for (int mt = 0; mt < 4; ++mt)
            #pragma unroll
            for (int r = 0; r < 4; ++r) {
                int row = m0 + mt * 16 + q * 4 + r;
                out[(size_t)row * ATT + col] = f2bf(fmaxf(acc[mt][nt][r] + bv, 0.f));
            }
    }
}

// ---------------- K5: x = out_bf @ Wt^T + b_mlp (MFMA, 64x64 tiles, 512 blocks) + BN stats ----------------
__global__ __launch_bounds__(256) void mlp_mfma_kernel(const ushort* __restrict__ A,   // [2048][1024] bf16
                                                       const ushort* __restrict__ Bt,  // [1024][1024] bf16
                                                       const float* __restrict__ bias,
                                                       float* __restrict__ X,
                                                       float* __restrict__ sums) {
    int t = threadIdx.x;
    int w = t >> 6, lane = t & 63;
    int lm = lane & 15, q = lane >> 4;
    int m0 = blockIdx.x * 64, n0 = blockIdx.y * 64;
    __shared__ __align__(16) ushort Asm[64][72];
    __shared__ __align__(16) ushort Bsm[64][72];

    floatx4 acc[4];
    #pragma unroll
    for (int mt = 0; mt < 4; ++mt) acc[mt] = (floatx4){0.f, 0.f, 0.f, 0.f};

    for (int k0 = 0; k0 < 1024; k0 += 64) {
        __syncthreads();
        #pragma unroll
        for (int i = 0; i < 4; ++i) {
            int flat = t + 256 * i;
            int r = flat >> 4, c4 = (flat & 15) * 4;
            *(uint2*)&Asm[r][c4] = *(const uint2*)&A[(size_t)(m0 + r) * 1024 + k0 + c4];
            *(uint2*)&Bsm[r][c4] = *(const uint2*)&Bt[(size_t)(n0 + r) * 1024 + k0 + c4];
        }
        __syncthreads();
        #pragma unroll
        for (int ks = 0; ks < 64; ks += 32) {
            short8 af[4], bfr;
            #pragma unroll
            for (int mt = 0; mt < 4; ++mt)
                af[mt] = *(const short8*)&Asm[mt * 16 + lm][ks + q * 8];
            bfr = *(const short8*)&Bsm[w * 16 + lm][ks + q * 8];
            #pragma unroll
            for (int mt = 0; mt < 4; ++mt)
                acc[mt] = __builtin_amdgcn_mfma_f32_16x16x32_bf16(af[mt], bfr, acc[mt], 0, 0, 0);
        }
    }
    int col = n0 + w * 16 + lm;
    float bv = bias[col];
    float s1 = 0.f, s2 = 0.f;
    #pragma unroll
    for (int mt = 0; mt < 4; ++mt)
        #pragma unroll
        for (int r = 0; r < 4; ++r) {
            int row = m0 + mt * 16 + q * 4 + r;
            float v = acc[mt][r] + bv;
            X[(size_t)row * 1024 + col] = v;
            s1 += v; s2 += v * v;
        }
    s1 += __shfl_xor(s1, 16); s1 += __shfl_xor(s1, 32);
    s2 += __shfl_xor(s2, 16); s2 += __shfl_xor(s2, 32);
    if (q == 0) {
        atomicAdd(&sums[col], s1);
        atomicAdd(&sums[ATT + col], s2);
    }
}

// ---------------- K6: normalize + relu -> d_out (float4) ----------------
__global__ __launch_bounds__(256) void bn_kernel(const float* __restrict__ X,
                                                 const float* __restrict__ sums,
                                                 const float* __restrict__ gamma,
                                                 const float* __restrict__ beta,
                                                 float* __restrict__ out) {
    size_t i4 = ((size_t)blockIdx.x * 256 + threadIdx.x) * 4;
    int f = (int)(i4 & 1023);
    float4 xv = *(const float4*)&X[i4];
    float4 s1 = *(const float4*)&sums[f];
    float4 s2 = *(const float4*)&sums[ATT + f];
    float4 gm = *(const float4*)&gamma[f];
    float4 bt = *(const float4*)&beta[f];
    float4 ov;
    float mu, var, v;
    mu = s1.x * (1.f / BB); var = s2.x * (1.f / BB) - mu * mu;
    v = (xv.x - mu) * rsqrtf(var + 1e-5f) * gm.x + bt.x; ov.x = v > 0.f ? v : 0.f;
    mu = s1.y * (1.f / BB); var = s2.y * (1.f / BB) - mu * mu;
    v = (xv.y - mu) * rsqrtf(var + 1e-5f) * gm.y + bt.y; ov.y = v > 0.f ? v : 0.f;
    mu = s1.z * (1.f / BB); var = s2.z * (1.f / BB) - mu * mu;
    v = (xv.z - mu) * rsqrtf(var + 1e-5f) * gm.z + bt.z; ov.z = v > 0.f ? v : 0.f;
    mu = s1.w * (1.f / BB); var = s2.w * (1.f / BB) - mu * mu;
    v = (xv.w - mu) * rsqrtf(var + 1e-5f) * gm.w + bt.w; ov.w = v > 0.f ? v : 0.f;
    *(float4*)&out[i4] = ov;
}

extern "C" void kernel_launch(void* const* d_in, const int* in_sizes, int n_in,
                              void* d_out, int out_size, void* d_ws, size_t ws_size,
                              hipStream_t stream) {
    const float* h        = (const float*)d_in[0];
    const float* end_pos  = (const float*)d_in[2];
    const float* rel_pos  = (const float*)d_in[3];
    const float* W_enc    = (const float*)d_in[4];
    const float* b_enc    = (const float*)d_in[5];
    const float* W_dec    = (const float*)d_in[6];
    const float* b_dec    = (const float*)d_in[7];
    const float* w_full   = (const float*)d_in[8];
    const float* b_full   = (const float*)d_in[9];
    const float* W_embed  = (const float*)d_in[10];
    const float* b_embed  = (const float*)d_in[11];
    const float* W_out    = (const float*)d_in[12];
    const float* b_out    = (const float*)d_in[13];
    const float* W_mlp    = (const float*)d_in[14];
    const float* b_mlp    = (const float*)d_in[15];
    const float* bn_gamma = (const float*)d_in[16];
    const float* bn_beta  = (const float*)d_in[17];

    float* ws = (float*)d_ws;
    ushort* enc     = (ushort*)ws;                 // 131072 x 64 bf16
    ushort* Wte     = (ushort*)(ws + 4259840);     // 1024 x 64 bf16
    ushort* Wot     = (ushort*)(ws + 4325376);     // 1024 x 96 bf16
    ushort* Wt      = (ushort*)(ws + 4374528);     // 1024 x 1024 bf16
    ushort* ctx_bf  = (ushort*)(ws + 4898816);     // 2048 x 96 bf16
    ushort* out_bf  = (ushort*)(ws + 4997120);     // 2048 x 1024 bf16
    float*  x       = ws + 6045696;                // 2048 x 1024 fp32
    float*  dec_r   = ws + 8388608;                // 2048 x 1024 fp32
    int*    rowidx  = (int*)(ws + 10485760);       // 131,072
    float*  score_c = ws + 10616832;               // 131,072
    int*    cntA    = (int*)(ws + 10747904);       // 2,048
    int*    baseA   = (int*)(ws + 10749952);       // 2,048
    int*    counter = (int*)(ws + 10752000);       // 64
    float*  sums    = ws + 10752064;               // 2,048
    float*  s_part  = ws + 10754112;               // 32 x 2048
    int*    flag    = (int*)(ws + 10819648);       // 64

    prep_kernel<<<K1_BLOCKS, 256, 0, stream>>>(h, end_pos, W_enc, W_dec, W_out, W_mlp,
                                               b_dec, b_enc, w_full,
                                               enc, Wte, Wot, Wt, dec_r, s_part,
                                               rowidx, cntA, baseA, counter, sums, flag);
    scoresC_mfma_kernel<<<MAXROWS / 64, 256, 0, stream>>>(enc, rowidx, counter, dec_r, Wte,
                                                          w_full, b_full, score_c);
    softmax_ctx_kernel<<<BB, 64, 0, stream>>>(score_c, rowidx, cntA, baseA, s_part, enc,
                                              end_pos, rel_pos, W_embed, b_embed, b_full, ctx_bf);
    out_mfma_kernel<<<dim3(32, 8), 256, 0, stream>>>(ctx_bf, Wot, b_out, out_bf);
    mlp_mfma_kernel<<<dim3(32, 16), 256, 0, stream>>>(out_bf, Wt, b_mlp, x, sums);
    bn_kernel<<<2048, 256, 0, stream>>>(x, sums, bn_gamma, bn_beta, (float*)d_out);
}